// Round 5
// baseline (1708.296 us; speedup 1.0000x reference)
//
#include <hip/hip_runtime.h>
#include <hip/hip_bf16.h>

// Fenwick TreeLSTM, N=32768, D=256 — fused GEMM+cell, DIRECT register loads.
// (M x 512) @ (512 x 1280) bf16 MFMA, fp32 accumulate. No LDS, no barriers:
// A and B fragments are loaded straight from global (L2-resident) into
// registers each K-step; 9 loads + 20 MFMA per step, fully unrolled.
// Gate-permuted W^T (n' = b*160 + g*32 + dl <-> col g*256 + b*32 + dl) puts
// all 5 gates of a (row, d) in one lane's accumulators for the fused cell.
// Phase-2 state_h double-buffered (sth read / sthN written) + merge kernel.

typedef unsigned short u16;
typedef unsigned int u32;
using short8  = __attribute__((ext_vector_type(8))) short;
using float4v = __attribute__((ext_vector_type(4))) float;

// ---- workspace layout (bytes) ----
// WmT  @ 0         : 1280x512 bf16 gate-permuted (1,310,720)
// WsT  @ 1310720   : 1280x512 bf16 gate-permuted (1,310,720)
// h0b  @ 2621440   : 32768x256 bf16 (16,777,216)
// hlv  @ 19398656  : levels 1..15 h bf16 (16,777,216)
// clv  @ 36175872  : levels 1..15 c fp32 (33,554,432)
// sth  @ 69730304  : state_h bf16, stable copy (16,777,216)
// sthN @ 86507520  : state_h bf16, iteration-k writes (16,777,216)

__device__ __forceinline__ u16 f2bf(float f) {
  u32 u = __float_as_uint(f);
  u = (u + 0x7FFFu + ((u >> 16) & 1u)) >> 16;
  return (u16)u;
}
__device__ __forceinline__ float bf2f(u16 h) {
  return __uint_as_float(((u32)h) << 16);
}
__device__ __forceinline__ float sigf(float x) { return 1.0f / (1.0f + __expf(-x)); }
__device__ __forceinline__ float tanhfast(float x) {
  return 2.0f / (1.0f + __expf(-2.0f * x)) - 1.0f;
}

// A-row gather: row i of A = concat(hl(256 bf16), hr(256 bf16)).
__device__ __forceinline__ void row_srcs(int mode, int k, int row,
                                         const u16* h0b, const u16* hlv, const u16* sth,
                                         const u16*& pL, const u16*& pR) {
  if (mode == 0) {
    const u16* pb = (k == 1) ? h0b : (hlv + (size_t)(32768 - (1 << (17 - k))) * 256);
    pL = pb + (size_t)(2 * row) * 256;
    pR = pb + (size_t)(2 * row + 1) * 256;
  } else {
    int t = ((row >> k) << (k + 1)) | (1 << k) | (row & ((1 << k) - 1));
    pL = sth + (size_t)(t - 1) * 256;
    int idx = (t >> (k + 1)) * 2;
    pR = hlv + (size_t)((32768 - (1 << (16 - k))) + idx) * 256;
  }
}

// Fused GEMM + LSTM cell, direct-load K-loop.
// Block tile: 128 rows x 160 cols (5 gates x 32 d), 16 K-steps of 32.
// 4 waves as 2(m) x 2(n): wave = 64 rows x 16 d's, acc[4 m-tiles][5 gates].
__global__ __launch_bounds__(256) void gemm_cell(
    int mode, int k, int Mc,
    const u16* WT, const float* bias,
    const u16* h0b, const u16* hlv, const u16* sth_in,
    const float* cpar, float* cout, u16* hout,
    const float* clv, float* out, u16* sth_out)
{
  const int tid  = threadIdx.x;
  const int lane = tid & 63;
  const int w    = tid >> 6;
  const int wm   = w >> 1, wn = w & 1;
  const int bm   = blockIdx.x, bn = blockIdx.y;
  const int mrow = lane & 15;   // row-in-16 / d-in-16
  const int kg   = lane >> 4;   // 8-elem K-group

  // per-lane A fragment source pointers: 4 m-tiles x (L, R), offset kg*8
  const u16 *aL[4], *aR[4];
#pragma unroll
  for (int mt = 0; mt < 4; ++mt) {
    int row = bm * 128 + wm * 64 + mt * 16 + mrow;
    if (row > Mc - 1) row = Mc - 1;
    const u16 *pl, *pr;
    row_srcs(mode, k, row, h0b, hlv, sth_in, pl, pr);
    aL[mt] = pl + kg * 8;
    aR[mt] = pr + kg * 8;
  }
  // per-lane B fragment source pointers: 5 gates
  const u16* bp[5];
#pragma unroll
  for (int g = 0; g < 5; ++g)
    bp[g] = WT + (size_t)(bn * 160 + g * 32 + wn * 16 + mrow) * 512 + kg * 8;

  float4v acc[4][5];
#pragma unroll
  for (int i = 0; i < 4; ++i)
#pragma unroll
    for (int j = 0; j < 5; ++j) acc[i][j] = (float4v){0.f, 0.f, 0.f, 0.f};

#pragma unroll
  for (int kk = 0; kk < 16; ++kk) {
    const int off = (kk & 7) * 32;     // K 0..255 from L, 256..511 from R
    short8 af[4], bfr[5];
#pragma unroll
    for (int mt = 0; mt < 4; ++mt)
      af[mt] = *(const short8*)(((kk < 8) ? aL[mt] : aR[mt]) + off);
#pragma unroll
    for (int g = 0; g < 5; ++g)
      bfr[g] = *(const short8*)(bp[g] + kk * 32);
#pragma unroll
    for (int mt = 0; mt < 4; ++mt)
#pragma unroll
      for (int g = 0; g < 5; ++g)
        acc[mt][g] = __builtin_amdgcn_mfma_f32_16x16x32_bf16(af[mt], bfr[g], acc[mt][g], 0, 0, 0);
  }

  // ---- fused cell epilogue ----
  // lane owns d = bn*32 + wn*16 + mrow; rows r0..r0+3 per m-tile.
  const int d = bn * 32 + wn * 16 + mrow;
  const float bi  = bias[d];
  const float bo  = bias[256 + d];
  const float bu  = bias[512 + d];
  const float bfl = bias[768 + d];
  const float bfr2= bias[1024 + d];

#pragma unroll
  for (int mt = 0; mt < 4; ++mt) {
    const int r0 = bm * 128 + wm * 64 + mt * 16 + kg * 4;
#pragma unroll
    for (int r = 0; r < 4; ++r) {
      const int row = r0 + r;
      if (row >= Mc) continue;
      const float zi  = acc[mt][0][r] + bi;
      const float zo  = acc[mt][1][r] + bo;
      const float zu  = acc[mt][2][r] + bu;
      const float zfl = acc[mt][3][r] + bfl;
      const float zfr = acc[mt][4][r] + bfr2;
      if (mode == 0) {
        const float cl = cpar[(size_t)(2 * row) * 256 + d];
        const float cr = cpar[(size_t)(2 * row + 1) * 256 + d];
        const float c = sigf(zi) * tanhfast(zu) + sigf(zfl) * cl + sigf(zfr) * cr;
        const float h = sigf(zo) * tanhfast(c);
        cout[(size_t)row * 256 + d] = c;
        hout[(size_t)row * 256 + d] = f2bf(h);
      } else {
        const int i  = row;
        const int t  = ((i >> k) << (k + 1)) | (1 << k) | (i & ((1 << k) - 1));
        const int lk = 32768 - (1 << (16 - k));
        const int idx = (t >> (k + 1)) * 2;
        const float cr = clv[(size_t)(lk + idx) * 256 + d];
        float h, c;
        if ((i & ((1 << k) - 1)) == 0) {
          h = bf2f(hlv[(size_t)(lk + idx) * 256 + d]);
          c = cr;
        } else {
          const float cl = out[(size_t)(t - 1) * 512 + 256 + d];
          c = sigf(zi) * tanhfast(zu) + sigf(zfl) * cl + sigf(zfr) * cr;
          h = sigf(zo) * tanhfast(c);
        }
        out[(size_t)(t - 1) * 512 + d] = h;
        out[(size_t)(t - 1) * 512 + 256 + d] = c;
        sth_out[(size_t)(t - 1) * 256 + d] = f2bf(h);
      }
    }
  }
}

// merge iteration-k state rows: sth[t-1] <- sthN[t-1] for all 16384 t's of iter k
__global__ __launch_bounds__(256) void merge_sth(
    int k, const u16* src, u16* dst)
{
  const int idx = blockIdx.x * 256 + threadIdx.x;   // 0..524287
  const int i = idx >> 5;
  const int s = (idx & 31) * 8;
  const int t = ((i >> k) << (k + 1)) | (1 << k) | (i & ((1 << k) - 1));
  *(short8*)(dst + (size_t)(t - 1) * 256 + s) = *(const short8*)(src + (size_t)(t - 1) * 256 + s);
}

// k=0: all odd t are first-touch copies of the leaves
__global__ __launch_bounds__(256) void copy_k0(
    const float* __restrict__ h_bot, const float* __restrict__ c_bot,
    float* __restrict__ out, u16* __restrict__ sth)
{
  const int i = blockIdx.x;          // 0..16383
  const int d = threadIdx.x;
  const int t = 2 * i + 1;
  const float h = h_bot[(size_t)(t - 1) * 256 + d];
  const float c = c_bot[(size_t)(t - 1) * 256 + d];
  out[(size_t)(t - 1) * 512 + d] = h;
  out[(size_t)(t - 1) * 512 + 256 + d] = c;
  sth[(size_t)(t - 1) * 256 + d] = f2bf(h);
}

// k=15: t=32768 copies level-15's single node (global row 32766)
__global__ __launch_bounds__(256) void copy_k15(
    const u16* __restrict__ hlv, const float* __restrict__ clv, float* __restrict__ out)
{
  const int d = threadIdx.x;
  out[(size_t)32767 * 512 + d] = bf2f(hlv[(size_t)32766 * 256 + d]);
  out[(size_t)32767 * 512 + 256 + d] = clv[(size_t)32766 * 256 + d];
}

// W (512x1280 fp32) -> gate-permuted W^T (1280x512 bf16).
// Output row n': b=n'/160, r=n'%160, g=r/32, dl=r%32 -> src col g*256 + b*32 + dl.
__global__ __launch_bounds__(256) void transpose_w(
    const float* __restrict__ W, u16* __restrict__ WT)
{
  const int n = blockIdx.x;          // 0..1279 (permuted)
  const int b = n / 160, r = n % 160;
  const int g = r / 32,  dl = r % 32;
  const int col = g * 256 + b * 32 + dl;
  const int tid = threadIdx.x;       // 0..255
  WT[(size_t)n * 512 + tid]       = f2bf(W[(size_t)tid * 1280 + col]);
  WT[(size_t)n * 512 + tid + 256] = f2bf(W[(size_t)(tid + 256) * 1280 + col]);
}

__global__ __launch_bounds__(256) void cast_h0(
    const float* __restrict__ h, u16* __restrict__ h0b)
{
  const size_t i = (size_t)blockIdx.x * 256 + threadIdx.x;
  h0b[i] = f2bf(h[i]);
}

extern "C" void kernel_launch(void* const* d_in, const int* in_sizes, int n_in,
                              void* d_out, int out_size, void* d_ws, size_t ws_size,
                              hipStream_t stream) {
  const float* h_bot = (const float*)d_in[0];
  const float* c_bot = (const float*)d_in[1];
  const float* Wm    = (const float*)d_in[2];
  const float* bmv   = (const float*)d_in[3];
  const float* Wsu   = (const float*)d_in[4];
  const float* bsv   = (const float*)d_in[5];
  float* out = (float*)d_out;
  char* ws = (char*)d_ws;

  u16*   WmT  = (u16*)(ws + 0);
  u16*   WsT  = (u16*)(ws + 1310720);
  u16*   h0b  = (u16*)(ws + 2621440);
  u16*   hlv  = (u16*)(ws + 19398656);
  float* clv  = (float*)(ws + 36175872);
  u16*   sth  = (u16*)(ws + 69730304);
  u16*   sthN = (u16*)(ws + 86507520);

  transpose_w<<<1280, 256, 0, stream>>>(Wm, WmT);
  transpose_w<<<1280, 256, 0, stream>>>(Wsu, WsT);
  cast_h0<<<32768, 256, 0, stream>>>(h_bot, h0b);

  // ---- phase 1: build tree levels (fused; race-free, disjoint levels) ----
  for (int kl = 1; kl <= 15; ++kl) {
    const int M = 32768 >> kl;
    const float* cpar = (kl == 1) ? c_bot : (clv + (size_t)(32768 - (1 << (17 - kl))) * 256);
    float* cout = clv + (size_t)(32768 - (1 << (16 - kl))) * 256;
    u16*   hout = hlv + (size_t)(32768 - (1 << (16 - kl))) * 256;
    dim3 grid((M + 127) / 128, 8);
    gemm_cell<<<grid, 256, 0, stream>>>(0, kl, M, WmT, bmv, h0b, hlv, sth,
                                        cpar, cout, hout, clv, out, sthN);
  }

  // ---- phase 2: Fenwick accumulation (fused; sth stable, sthN written) ----
  copy_k0<<<16384, 256, 0, stream>>>(h_bot, c_bot, out, sth);
  for (int kl = 1; kl <= 14; ++kl) {
    dim3 grid(128, 8);
    gemm_cell<<<grid, 256, 0, stream>>>(1, kl, 16384, WsT, bsv, h0b, hlv, sth,
                                        nullptr, nullptr, nullptr, clv, out, sthN);
    merge_sth<<<2048, 256, 0, stream>>>(kl, sthN, sth);
  }
  copy_k15<<<1, 256, 0, stream>>>(hlv, clv, out);
}

// Round 6
// 1458.127 us; speedup vs baseline: 1.1716x; 1.1716x over previous
//
#include <hip/hip_runtime.h>
#include <hip/hip_bf16.h>

// Fenwick TreeLSTM, N=32768, D=256 — fused GEMM+cell, contiguous-A staging.
// (M x 512) @ (512 x 1280) bf16 MFMA, fp32 accumulate.
// - A is always contiguous row-major (phase 1: level k-1 pairs are adjacent;
//   phase 2: a pre-gather kernel packs [state_h | node_h] rows).
// - LDS holds A/B tiles in MFMA-FRAGMENT order (slot = [tile][kg][mrow]) so
//   ds_read_b128 is lane-linear -> no bank conflicts. global_load_lds sources
//   are per-lane gathers; LDS bases are wave-uniform.
// - Gate-permuted W^T (n' = b*160 + g*32 + dl <-> col g*256 + b*32 + dl).
// - Phase 2 keeps state in sth (bf16 h) + stc (fp32 c); `out` written only
//   when a row is finalized (i < 2^k). Pre-gather makes state access race-free.

typedef unsigned short u16;
typedef unsigned int u32;
using short8  = __attribute__((ext_vector_type(8))) short;
using float4v = __attribute__((ext_vector_type(4))) float;

// ---- workspace layout (bytes) ----
// WmT  @ 0         : 1280x512 bf16 gate-permuted (1,310,720)
// WsT  @ 1310720   : 1280x512 bf16 gate-permuted (1,310,720)
// h0b  @ 2621440   : 32768x256 bf16 (16,777,216)  [phase 2 reuses as Ag 16384x512]
// hlv  @ 19398656  : levels 1..15 h bf16 (16,777,216)
// clv  @ 36175872  : levels 1..15 c fp32 (33,554,432)
// sth  @ 69730304  : state_h bf16 (16,777,216)
// stc  @ 86507520  : state_c fp32 (33,554,432)
// total ~120 MB

__device__ __forceinline__ u16 f2bf(float f) {
  u32 u = __float_as_uint(f);
  u = (u + 0x7FFFu + ((u >> 16) & 1u)) >> 16;
  return (u16)u;
}
__device__ __forceinline__ float bf2f(u16 h) {
  return __uint_as_float(((u32)h) << 16);
}
__device__ __forceinline__ float sigf(float x) { return 1.0f / (1.0f + __expf(-x)); }
__device__ __forceinline__ float tanhfast(float x) {
  return 2.0f / (1.0f + __expf(-2.0f * x)) - 1.0f;
}

__device__ __forceinline__ void async16(const void* g, void* l) {
  __builtin_amdgcn_global_load_lds((const __attribute__((address_space(1))) void*)g,
                                   (__attribute__((address_space(3))) void*)l,
                                   16, 0, 0);
}

// Fused GEMM + LSTM cell. A contiguous row-major (512 u16/row).
// Block tile: 128 rows x 160 cols (5 gates x 32 d), BK=32, 16 K-steps.
// 4 waves as 2(m) x 2(n): wave = 64 rows x 16 d's, acc[4 m-tiles][5 gates].
// LDS fragment-order: A slot s(0..511) = wm*256 + mt*64 + kg*16 + mrow
//                     B slot s(0..639) = g*128 + wn*64 + kg*16 + mrow
__global__ __launch_bounds__(256) void gemm_cell(
    int mode, int k, int Mc,
    const u16* A, const u16* WT, const float* bias,
    const float* cpar, float* cout, u16* hout,
    const float* clv, float* stc, float* out, u16* sth)
{
  __shared__ __align__(16) u16 smem[9216];  // A u16[0,4096)  B u16[4096,9216)
  const int tid  = threadIdx.x;
  const int lane = tid & 63;
  const int w    = tid >> 6;
  const int wm   = w >> 1, wn = w & 1;
  const int bm   = blockIdx.x, bn = blockIdx.y;
  const int mrow = lane & 15;
  const int kg   = lane >> 4;

  // ---- A staging: 512 slots in 2 rounds; slot sA0 = tid, sA1 = tid + 256 ----
  // decode slot s: row = (s>>8)*64 + ((s>>6)&3)*16 + (s&15), seg = (s>>4)&3
  const int sA0 = tid, sA1 = tid + 256;
  int rowS0 = ((sA0 >> 8) & 1) * 64 + ((sA0 >> 6) & 3) * 16 + (sA0 & 15);
  int rowS1 = ((sA1 >> 8) & 1) * 64 + ((sA1 >> 6) & 3) * 16 + (sA1 & 15);
  int rg0 = bm * 128 + rowS0; if (rg0 > Mc - 1) rg0 = Mc - 1;
  int rg1 = bm * 128 + rowS1; if (rg1 > Mc - 1) rg1 = Mc - 1;
  const u16* pA0 = A + (size_t)rg0 * 512 + ((sA0 >> 4) & 3) * 8;
  const u16* pA1 = A + (size_t)rg1 * 512 + ((sA1 >> 4) & 3) * 8;
  u16* dA0 = smem + w * 512;          // wave-uniform (byte w*1024)
  u16* dA1 = smem + 2048 + w * 512;

  // ---- B staging: 640 slots in 2.5 rounds; slot = r*256 + tid (r=0,1), 512+tid (tid<128)
  // decode: g = s>>7, wn = (s>>6)&1, kg = (s>>4)&3, mrow = s&15
  const int sB0 = tid, sB1 = tid + 256, sB2 = tid + 512;   // sB2 valid tid<128
  const u16* pB0 = WT + (size_t)(bn * 160 + (sB0 >> 7) * 32 + ((sB0 >> 6) & 1) * 16 + (sB0 & 15)) * 512 + ((sB0 >> 4) & 3) * 8;
  const u16* pB1 = WT + (size_t)(bn * 160 + (sB1 >> 7) * 32 + ((sB1 >> 6) & 1) * 16 + (sB1 & 15)) * 512 + ((sB1 >> 4) & 3) * 8;
  const u16* pB2 = WT + (size_t)(bn * 160 + (sB2 >> 7) * 32 + ((sB2 >> 6) & 1) * 16 + (sB2 & 15)) * 512 + ((sB2 >> 4) & 3) * 8;
  u16* dB0 = smem + 4096 + w * 512;            // slots 0..255   (byte 8192 + w*1024)
  u16* dB1 = smem + 6144 + w * 512;            // slots 256..511
  u16* dB2 = smem + 8192 + w * 512;            // slots 512..639 (waves 0,1)

  float4v acc[4][5];
#pragma unroll
  for (int i = 0; i < 4; ++i)
#pragma unroll
    for (int j = 0; j < 5; ++j) acc[i][j] = (float4v){0.f, 0.f, 0.f, 0.f};

  // fragment read bases (lane-linear 16B stride -> conflict-free)
  const u16* aBase = smem + (wm * 256 + kg * 16 + mrow) * 8;           // + mt*512
  const u16* bBase = smem + 4096 + (wn * 64 + kg * 16 + mrow) * 8;     // + g*1024

  for (int kk = 0; kk < 16; ++kk) {
    const int ko = kk * 32;
    async16(pA0 + ko, dA0);
    async16(pA1 + ko, dA1);
    async16(pB0 + ko, dB0);
    async16(pB1 + ko, dB1);
    if (tid < 128) async16(pB2 + ko, dB2);
    __syncthreads();
    short8 af[4], bfr[5];
#pragma unroll
    for (int mt = 0; mt < 4; ++mt) af[mt]  = *(const short8*)(aBase + mt * 512);
#pragma unroll
    for (int g = 0; g < 5; ++g)   bfr[g]  = *(const short8*)(bBase + g * 1024);
#pragma unroll
    for (int mt = 0; mt < 4; ++mt)
#pragma unroll
      for (int g = 0; g < 5; ++g)
        acc[mt][g] = __builtin_amdgcn_mfma_f32_16x16x32_bf16(af[mt], bfr[g], acc[mt][g], 0, 0, 0);
    __syncthreads();
  }

  // ---- fused cell epilogue ----
  // lane owns d = bn*32 + wn*16 + mrow; rows r0..r0+3 per m-tile.
  const int d = bn * 32 + wn * 16 + mrow;
  const float bi  = bias[d];
  const float bo  = bias[256 + d];
  const float bu  = bias[512 + d];
  const float bfl = bias[768 + d];
  const float bfr2= bias[1024 + d];

#pragma unroll
  for (int mt = 0; mt < 4; ++mt) {
    const int r0 = bm * 128 + wm * 64 + mt * 16 + kg * 4;
#pragma unroll
    for (int r = 0; r < 4; ++r) {
      const int row = r0 + r;
      if (row >= Mc) continue;
      const float zi  = acc[mt][0][r] + bi;
      const float zo  = acc[mt][1][r] + bo;
      const float zu  = acc[mt][2][r] + bu;
      const float zfl = acc[mt][3][r] + bfl;
      const float zfr = acc[mt][4][r] + bfr2;
      if (mode == 0) {
        const float cl = cpar[(size_t)(2 * row) * 256 + d];
        const float cr = cpar[(size_t)(2 * row + 1) * 256 + d];
        const float c = sigf(zi) * tanhfast(zu) + sigf(zfl) * cl + sigf(zfr) * cr;
        const float h = sigf(zo) * tanhfast(c);
        cout[(size_t)row * 256 + d] = c;
        hout[(size_t)row * 256 + d] = f2bf(h);
      } else {
        const int i  = row;
        const int t  = ((i >> k) << (k + 1)) | (1 << k) | (i & ((1 << k) - 1));
        const int lk = 32768 - (1 << (16 - k));
        const int idx = (t >> (k + 1)) * 2;
        const float cr = clv[(size_t)(lk + idx) * 256 + d];
        float h, c;
        if ((i & ((1 << k) - 1)) == 0) {
          h = bf2f(A[(size_t)i * 512 + 256 + d]);   // node h (gathered)
          c = cr;
        } else {
          const float cl = stc[(size_t)(t - 1) * 256 + d];
          c = sigf(zi) * tanhfast(zu) + sigf(zfl) * cl + sigf(zfr) * cr;
          h = sigf(zo) * tanhfast(c);
        }
        sth[(size_t)(t - 1) * 256 + d] = f2bf(h);
        stc[(size_t)(t - 1) * 256 + d] = c;
        if ((i >> k) == 0) {   // t in [2^k, 2^(k+1)) -> final value for this row
          out[(size_t)(t - 1) * 512 + d] = h;
          out[(size_t)(t - 1) * 512 + 256 + d] = c;
        }
      }
    }
  }
}

// phase-2 pre-gather: Ag[i] = [ sth[t-1] | hlv[node(k,i)] ], 16 B per thread
__global__ __launch_bounds__(256) void gather_A(
    int k, const u16* sth, const u16* hlv, u16* Ag)
{
  const int s = blockIdx.x * 256 + threadIdx.x;   // 0 .. 16384*64-1
  const int i = s >> 6;
  const int q = s & 63;
  const int t = ((i >> k) << (k + 1)) | (1 << k) | (i & ((1 << k) - 1));
  const u16* src;
  if (q < 32) {
    src = sth + (size_t)(t - 1) * 256 + q * 8;
  } else {
    const int lk = 32768 - (1 << (16 - k));
    const int idx = (t >> (k + 1)) * 2;
    src = hlv + (size_t)(lk + idx) * 256 + (q - 32) * 8;
  }
  *(short8*)(Ag + (size_t)i * 512 + q * 8) = *(const short8*)src;
}

// k=0: init state for all odd t; only t=1 is final
__global__ __launch_bounds__(256) void copy_k0(
    const float* __restrict__ h_bot, const float* __restrict__ c_bot,
    float* __restrict__ out, u16* __restrict__ sth, float* __restrict__ stc)
{
  const int i = blockIdx.x;          // 0..16383
  const int d = threadIdx.x;
  const int t = 2 * i + 1;
  const float h = h_bot[(size_t)(t - 1) * 256 + d];
  const float c = c_bot[(size_t)(t - 1) * 256 + d];
  sth[(size_t)(t - 1) * 256 + d] = f2bf(h);
  stc[(size_t)(t - 1) * 256 + d] = c;
  if (i == 0) {
    out[d] = h;
    out[256 + d] = c;
  }
}

// k=15: t=32768 copies level-15's single node (global row 32766)
__global__ __launch_bounds__(256) void copy_k15(
    const u16* __restrict__ hlv, const float* __restrict__ clv, float* __restrict__ out)
{
  const int d = threadIdx.x;
  out[(size_t)32767 * 512 + d] = bf2f(hlv[(size_t)32766 * 256 + d]);
  out[(size_t)32767 * 512 + 256 + d] = clv[(size_t)32766 * 256 + d];
}

// W (512x1280 fp32) -> gate-permuted W^T (1280x512 bf16).
// Output row n': b=n'/160, r=n'%160, g=r/32, dl=r%32 -> src col g*256 + b*32 + dl.
__global__ __launch_bounds__(256) void transpose_w(
    const float* __restrict__ W, u16* __restrict__ WT)
{
  const int n = blockIdx.x;          // 0..1279 (permuted)
  const int b = n / 160, r = n % 160;
  const int g = r / 32,  dl = r % 32;
  const int col = g * 256 + b * 32 + dl;
  const int tid = threadIdx.x;       // 0..255
  WT[(size_t)n * 512 + tid]       = f2bf(W[(size_t)tid * 1280 + col]);
  WT[(size_t)n * 512 + tid + 256] = f2bf(W[(size_t)(tid + 256) * 1280 + col]);
}

__global__ __launch_bounds__(256) void cast_h0(
    const float* __restrict__ h, u16* __restrict__ h0b)
{
  const size_t i = (size_t)blockIdx.x * 256 + threadIdx.x;
  h0b[i] = f2bf(h[i]);
}

extern "C" void kernel_launch(void* const* d_in, const int* in_sizes, int n_in,
                              void* d_out, int out_size, void* d_ws, size_t ws_size,
                              hipStream_t stream) {
  const float* h_bot = (const float*)d_in[0];
  const float* c_bot = (const float*)d_in[1];
  const float* Wm    = (const float*)d_in[2];
  const float* bmv   = (const float*)d_in[3];
  const float* Wsu   = (const float*)d_in[4];
  const float* bsv   = (const float*)d_in[5];
  float* out = (float*)d_out;
  char* ws = (char*)d_ws;

  u16*   WmT = (u16*)(ws + 0);
  u16*   WsT = (u16*)(ws + 1310720);
  u16*   h0b = (u16*)(ws + 2621440);        // phase-2 alias: Ag (16384x512 bf16)
  u16*   hlv = (u16*)(ws + 19398656);
  float* clv = (float*)(ws + 36175872);
  u16*   sth = (u16*)(ws + 69730304);
  float* stc = (float*)(ws + 86507520);
  u16*   Ag  = h0b;                          // h0b dead after phase-1 level 1

  transpose_w<<<1280, 256, 0, stream>>>(Wm, WmT);
  transpose_w<<<1280, 256, 0, stream>>>(Wsu, WsT);
  cast_h0<<<32768, 256, 0, stream>>>(h_bot, h0b);

  // ---- phase 1: build tree levels (A = contiguous level k-1 rows) ----
  for (int kl = 1; kl <= 15; ++kl) {
    const int M = 32768 >> kl;
    const u16* Abase = (kl == 1) ? h0b : (hlv + (size_t)(32768 - (1 << (17 - kl))) * 256);
    const float* cpar = (kl == 1) ? c_bot : (clv + (size_t)(32768 - (1 << (17 - kl))) * 256);
    float* cout = clv + (size_t)(32768 - (1 << (16 - kl))) * 256;
    u16*   hout = hlv + (size_t)(32768 - (1 << (16 - kl))) * 256;
    dim3 grid((M + 127) / 128, 8);
    gemm_cell<<<grid, 256, 0, stream>>>(0, kl, M, Abase, WmT, bmv,
                                        cpar, cout, hout,
                                        nullptr, nullptr, nullptr, nullptr);
  }

  // ---- phase 2: Fenwick accumulation (gather -> fused GEMM+cell) ----
  copy_k0<<<16384, 256, 0, stream>>>(h_bot, c_bot, out, sth, stc);
  for (int kl = 1; kl <= 14; ++kl) {
    gather_A<<<4096, 256, 0, stream>>>(kl, sth, hlv, Ag);
    dim3 grid(128, 8);
    gemm_cell<<<grid, 256, 0, stream>>>(1, kl, 16384, Ag, WsT, bsv,
                                        nullptr, nullptr, nullptr,
                                        clv, stc, out, sth);
  }
  copy_k15<<<1, 256, 0, stream>>>(hlv, clv, out);
}